// Round 1
// baseline (7739.410 us; speedup 1.0000x reference)
//
#include <hip/hip_runtime.h>

constexpr int T_SEQ = 168;
constexpr int DIN   = 16;
constexpr int H1    = 64;
constexpr int H2    = 32;
constexpr int NB    = 16;   // batch tile per block

__device__ __forceinline__ float fast_rcp(float v) { return __builtin_amdgcn_rcpf(v); }
__device__ __forceinline__ float fsigmoid(float v) { return fast_rcp(1.f + __expf(-v)); }
__device__ __forceinline__ float ftanh(float v)    { return 2.f * fast_rcp(1.f + __expf(-2.f * v)) - 1.f; }

__device__ __forceinline__ float dot4(float4 a, float4 b, float acc) {
  acc = fmaf(a.x, b.x, acc);
  acc = fmaf(a.y, b.y, acc);
  acc = fmaf(a.z, b.z, acc);
  acc = fmaf(a.w, b.w, acc);
  return acc;
}

__global__ __launch_bounds__(256, 1)
void lstm_fused_kernel(const float* __restrict__ x,
    const float* __restrict__ Wih1, const float* __restrict__ Whh1,
    const float* __restrict__ bih1, const float* __restrict__ bhh1,
    const float* __restrict__ Wih2, const float* __restrict__ Whh2,
    const float* __restrict__ bih2, const float* __restrict__ bhh2,
    const float* __restrict__ Wfc,  const float* __restrict__ bfc,
    float* __restrict__ out)
{
  __shared__ __align__(16) float sH1[NB][H1];      // h1 state, [batch][unit]
  __shared__ __align__(16) float sH2[NB][H2];      // h2 state
  __shared__ __align__(16) float sG1[4][NB][H1];   // L1 gate activations [type][batch][unit]
  __shared__ __align__(16) float sG2[4][NB][H2];   // L2 gate activations
  __shared__ __align__(16) float sX[NB][DIN];      // current x_t tile
  __shared__ __align__(16) float sB1[4*H1];        // b_ih1+b_hh1
  __shared__ __align__(16) float sB2[4*H2];        // b_ih2+b_hh2

  const int u  = threadIdx.x;
  const int b0 = blockIdx.x * NB;

  // phase-2 mapping (L1 gates): thread owns 2 gate rows x 8 batches
  const int j1 = u & 63;          // hidden unit
  const int p  = (u >> 6) & 1;    // 0 -> rows {j, 128+j} (i,g); 1 -> rows {64+j, 192+j} (f,o)
  const int bh = u >> 7;          // batch half (8 batches)
  const int rA = p * 64 + j1;
  const int rB = rA + 128;

  // phase-4 mapping (L2 gates): thread owns 1 gate row x 8 batches
  const int r2  = u & 127;
  const int g2t = r2 >> 5;        // gate type 0..3
  const int j2w = r2 & 31;

  // phase-3 mapping (L1 state): (unit j1, batches bq+4n)
  const int bq = u >> 6;          // 0..3

  // phase-5 mapping (L2 state): (unit j2s, batches bo+8n)
  const int j2s = u & 31;
  const int bo  = u >> 5;         // 0..7

  // ---- weights into registers (reused for all 168 steps) ----
  float4 wA[16], wB[16];          // W_hh1 rows rA, rB
  {
    const float4* W = (const float4*)Whh1;
    #pragma unroll
    for (int k = 0; k < 16; ++k) { wA[k] = W[rA*16 + k]; wB[k] = W[rB*16 + k]; }
  }
  float4 wxA[4], wxB[4];          // W_ih1 rows rA, rB
  {
    const float4* W = (const float4*)Wih1;
    #pragma unroll
    for (int k = 0; k < 4; ++k) { wxA[k] = W[rA*4 + k]; wxB[k] = W[rB*4 + k]; }
  }
  float4 w2i[16];                 // W_ih2 row r2
  {
    const float4* W = (const float4*)Wih2;
    #pragma unroll
    for (int k = 0; k < 16; ++k) w2i[k] = W[r2*16 + k];
  }
  float4 w2h[8];                  // W_hh2 row r2
  {
    const float4* W = (const float4*)Whh2;
    #pragma unroll
    for (int k = 0; k < 8; ++k) w2h[k] = W[r2*8 + k];
  }

  // ---- biases + zero states ----
  sB1[u] = bih1[u] + bhh1[u];
  if (u < 4*H2) sB2[u] = bih2[u] + bhh2[u];
  {
    float4 z = make_float4(0.f, 0.f, 0.f, 0.f);
    ((float4*)sH1)[u] = z;                       // 16*64/4 = 256
    if (u < NB*H2/4) ((float4*)sH2)[u] = z;      // 128
  }
  { // x(t=0)
    const int bb = u >> 4, d = u & 15;
    sX[bb][d] = x[(b0+bb)*(T_SEQ*DIN) + d];
  }
  __syncthreads();

  const float bA1 = sB1[rA], bB1 = sB1[rB];
  const float b2v = sB2[r2];

  float c1s[4] = {0.f, 0.f, 0.f, 0.f};
  float c2s[2] = {0.f, 0.f};

  for (int t = 0; t < T_SEQ; ++t) {
    // ================= phase 2: L1 gate pre-acts + activations =================
    float accA[8], accB[8];
    #pragma unroll
    for (int b = 0; b < 8; ++b) { accA[b] = bA1; accB[b] = bB1; }
    #pragma unroll
    for (int d4 = 0; d4 < 4; ++d4) {
      const float4 wa = wxA[d4], wb = wxB[d4];
      #pragma unroll
      for (int b = 0; b < 8; ++b) {
        const float4 xv = *(const float4*)&sX[bh*8+b][d4*4];
        accA[b] = dot4(wa, xv, accA[b]);
        accB[b] = dot4(wb, xv, accB[b]);
      }
    }
    #pragma unroll
    for (int k4 = 0; k4 < 16; ++k4) {
      const float4 wa = wA[k4], wb = wB[k4];
      #pragma unroll
      for (int b = 0; b < 8; ++b) {
        const float4 hv = *(const float4*)&sH1[bh*8+b][k4*4];
        accA[b] = dot4(wa, hv, accA[b]);
        accB[b] = dot4(wb, hv, accB[b]);
      }
    }
    if (p == 0) {            // rows: i (sigmoid), g (tanh)
      #pragma unroll
      for (int b = 0; b < 8; ++b) {
        sG1[0][bh*8+b][j1] = fsigmoid(accA[b]);
        sG1[2][bh*8+b][j1] = ftanh(accB[b]);
      }
    } else {                 // rows: f (sigmoid), o (sigmoid)
      #pragma unroll
      for (int b = 0; b < 8; ++b) {
        sG1[1][bh*8+b][j1] = fsigmoid(accA[b]);
        sG1[3][bh*8+b][j1] = fsigmoid(accB[b]);
      }
    }
    __syncthreads();

    // ================= phase 3: L1 state update =================
    #pragma unroll
    for (int n = 0; n < 4; ++n) {
      const int b = bq + n*4;
      const float iv = sG1[0][b][j1];
      const float fv = sG1[1][b][j1];
      const float gv = sG1[2][b][j1];
      const float ov = sG1[3][b][j1];
      const float c  = fmaf(fv, c1s[n], iv * gv);
      c1s[n] = c;
      sH1[b][j1] = ov * ftanh(c);
    }
    __syncthreads();

    // ================= phase 4: L2 gate pre-acts + activations =================
    float acc2[8];
    #pragma unroll
    for (int b = 0; b < 8; ++b) acc2[b] = b2v;
    #pragma unroll
    for (int k4 = 0; k4 < 16; ++k4) {
      const float4 wv = w2i[k4];
      #pragma unroll
      for (int b = 0; b < 8; ++b) {
        const float4 hv = *(const float4*)&sH1[bh*8+b][k4*4];
        acc2[b] = dot4(wv, hv, acc2[b]);
      }
    }
    #pragma unroll
    for (int k4 = 0; k4 < 8; ++k4) {
      const float4 wv = w2h[k4];
      #pragma unroll
      for (int b = 0; b < 8; ++b) {
        const float4 hv = *(const float4*)&sH2[bh*8+b][k4*4];
        acc2[b] = dot4(wv, hv, acc2[b]);
      }
    }
    {
      const bool isg = (g2t == 2);
      #pragma unroll
      for (int b = 0; b < 8; ++b) {
        const float a   = acc2[b];
        const float act = isg ? ftanh(a) : fsigmoid(a);
        sG2[g2t][bh*8+b][j2w] = act;
      }
    }
    __syncthreads();

    // ================= phase 5: L2 state update (+ x prefetch) =================
    #pragma unroll
    for (int n = 0; n < 2; ++n) {
      const int b = bo + n*8;
      const float iv = sG2[0][b][j2s];
      const float fv = sG2[1][b][j2s];
      const float gv = sG2[2][b][j2s];
      const float ov = sG2[3][b][j2s];
      const float c  = fmaf(fv, c2s[n], iv * gv);
      c2s[n] = c;
      sH2[b][j2s] = ov * ftanh(c);
    }
    if (t + 1 < T_SEQ) {
      const int bb = u >> 4, d = u & 15;
      sX[bb][d] = x[(b0+bb)*(T_SEQ*DIN) + (t+1)*DIN + d];
    }
    __syncthreads();
  }

  // ================= final FC on last h2 =================
  if (u < NB) {
    float s = bfc[0];
    #pragma unroll
    for (int j = 0; j < H2; ++j) s = fmaf(Wfc[j], sH2[u][j], s);
    out[b0 + u] = s;
  }
}

extern "C" void kernel_launch(void* const* d_in, const int* in_sizes, int n_in,
                              void* d_out, int out_size, void* d_ws, size_t ws_size,
                              hipStream_t stream) {
  const float* x    = (const float*)d_in[0];
  const float* Wih1 = (const float*)d_in[1];
  const float* Whh1 = (const float*)d_in[2];
  const float* bih1 = (const float*)d_in[3];
  const float* bhh1 = (const float*)d_in[4];
  const float* Wih2 = (const float*)d_in[5];
  const float* Whh2 = (const float*)d_in[6];
  const float* bih2 = (const float*)d_in[7];
  const float* bhh2 = (const float*)d_in[8];
  const float* Wfc  = (const float*)d_in[9];
  const float* bfc  = (const float*)d_in[10];
  float* out = (float*)d_out;

  dim3 grid(4096 / NB);   // 256 blocks -> 1 per CU
  dim3 block(256);
  hipLaunchKernelGGL(lstm_fused_kernel, grid, block, 0, stream,
                     x, Wih1, Whh1, bih1, bhh1, Wih2, Whh2, bih2, bhh2, Wfc, bfc, out);
}

// Round 2
// 355.163 us; speedup vs baseline: 21.7911x; 21.7911x over previous
//
#include <hip/hip_runtime.h>

// 2-layer LSTM, B=4096, T=168, D=16, H1=64, H2=32, fp32 in/out.
// Strategy: persistent fused kernel, 256 blocks x 256 threads (1 block/CU),
// NB=16 batches/block => M=16 exactly one MFMA tile. All matmuls via
// mfma_f32_16x16x32_bf16 with hi/lo bf16 split (2-pass, exact product of
// reconstructed values, fp32 accumulate). Weights live in registers as
// B-fragments (W_ih2 staged in LDS); h1/h2/x live in LDS in A-fragment order
// so every fragment load is one conflict-free ds_read_b128.

typedef __bf16 bf16x8 __attribute__((ext_vector_type(8)));
typedef float  f32x4  __attribute__((ext_vector_type(4)));

constexpr int T_SEQ = 168;
constexpr int DIN   = 16;
constexpr int NB    = 16;

__device__ __forceinline__ float fsig(float v)  { return __builtin_amdgcn_rcpf(1.f + __expf(-v)); }
__device__ __forceinline__ float ftanhf(float v){ return 2.f * __builtin_amdgcn_rcpf(1.f + __expf(-2.f * v)) - 1.f; }

__device__ __forceinline__ void split_bf16(float x, __bf16& hi, __bf16& lo) {
  hi = (__bf16)x;
  lo = (__bf16)(x - (float)hi);
}

// Load 8 consecutive floats of a weight row starting at k0; emit hi/lo bf16 frags.
__device__ __forceinline__ void load_frag8(const float* __restrict__ Wrow, int k0,
                                           bf16x8& hi, bf16x8& lo) {
#pragma unroll
  for (int j = 0; j < 8; ++j) {
    float v = Wrow[k0 + j];
    __bf16 h = (__bf16)v;
    hi[j] = h;
    lo[j] = (__bf16)(v - (float)h);
  }
}

#define MFMA(a, b, c) __builtin_amdgcn_mfma_f32_16x16x32_bf16((a), (b), (c), 0, 0, 0)

__global__ __launch_bounds__(256, 1)
void lstm_mfma_kernel(const float* __restrict__ x,
    const float* __restrict__ Wih1, const float* __restrict__ Whh1,
    const float* __restrict__ bih1, const float* __restrict__ bhh1,
    const float* __restrict__ Wih2, const float* __restrict__ Whh2,
    const float* __restrict__ bih2, const float* __restrict__ bhh2,
    const float* __restrict__ Wfc,  const float* __restrict__ bfc,
    float* __restrict__ out)
{
  // A-fragment tiles, stored in exact lane order: [kb][lane][j] (j = 8 bf16 = 16B/lane)
  __shared__ __align__(16) __bf16 sA1[4 * 64 * 8];   // h1 hi(kb0,1)/lo(kb2,3), K=128 logical
  __shared__ __align__(16) __bf16 sA2[2 * 64 * 8];   // h2 hi(kb0)/lo(kb1),      K=64 logical
  __shared__ __align__(16) __bf16 sAX[2 * 64 * 8];   // x: p0=[xh|xl], p1=[xl|xh], K=32
  __shared__ __align__(16) __bf16 sB2[8 * 4 * 64 * 8]; // W_ih2 B-frags [nt][kb][lane][j] (32 KB)
  __shared__ __align__(16) float  sH2f[16 * 32];     // final-step h2, plain [batch][unit]

  const int tid  = threadIdx.x;
  const int w    = tid >> 6;        // wave 0..3
  const int lane = tid & 63;
  const int q    = lane >> 4;       // quad 0..3
  const int col  = lane & 15;
  const int b0   = blockIdx.x * NB;

  // ---------------- B-fragment (weight) setup: registers ----------------
  // L1: wave w owns units [w*16, w*16+16); N-tiles = gate types g=0..3, row = g*64 + w*16 + col
  bf16x8 bhh[4][4];   // W_hh1, K=128 (hi kb0,1 | lo kb2,3)
  bf16x8 bih[4];      // W_ih1, K=32 packed [Wh(0..15); Wl(0..15)]
  float  b1v[4];
#pragma unroll
  for (int g = 0; g < 4; ++g) {
    const int r = g * 64 + w * 16 + col;
    const float* Wr = Whh1 + r * 64;
    bf16x8 h0, l0, h1f, l1f;
    load_frag8(Wr, 0 * 32 + q * 8, h0, l0);
    load_frag8(Wr, 1 * 32 + q * 8, h1f, l1f);
    bhh[g][0] = h0; bhh[g][1] = h1f; bhh[g][2] = l0; bhh[g][3] = l1f;
    const float* Wxr = Wih1 + r * 16;
    bf16x8 xh, xl;
    load_frag8(Wxr, (q & 1) * 8, xh, xl);
    bih[g] = (q < 2) ? xh : xl;   // k<16 -> hi, k>=16 -> lo
    b1v[g] = bih1[r] + bhh1[r];
  }
  // L2 (waves 0,1 only): wave w owns units [w*16, w*16+16); row = g*32 + w*16 + col
  bf16x8 bh2[4][2];   // W_hh2, K=64 (hi kb0 | lo kb1)
  float  b2v[4] = {0.f, 0.f, 0.f, 0.f};
  if (w < 2) {
#pragma unroll
    for (int g = 0; g < 4; ++g) {
      const int r = g * 32 + w * 16 + col;
      bf16x8 hh, ll;
      load_frag8(Whh2 + r * 32, q * 8, hh, ll);
      bh2[g][0] = hh; bh2[g][1] = ll;
      b2v[g] = bih2[r] + bhh2[r];
    }
  }

  // ---------------- LDS staging: W_ih2 B-frags ----------------
  for (int idx = tid; idx < 8 * 4 * 64; idx += 256) {
    const int nt = idx >> 8;          // 0..7  (= g*2 + wv)
    const int kb = (idx >> 6) & 3;
    const int ln = idx & 63;
    const int qq = ln >> 4, cc = ln & 15;
    const int g  = nt >> 1, wv = nt & 1;
    const int r  = g * 32 + wv * 16 + cc;
    const int k0 = (kb & 1) * 32 + qq * 8;
    bf16x8 hh, ll;
    load_frag8(Wih2 + r * 64, k0, hh, ll);
    *(bf16x8*)&sB2[((nt * 4 + kb) * 64 + ln) * 8] = (kb < 2) ? hh : ll;
  }

  // ---------------- zero h states in LDS, stage x(0) ----------------
  {
    bf16x8 z;
#pragma unroll
    for (int j = 0; j < 8; ++j) z[j] = (__bf16)0.f;
    for (int i = tid; i < 4 * 64; i += 256) *(bf16x8*)&sA1[i * 8] = z;
    for (int i = tid; i < 2 * 64; i += 256) *(bf16x8*)&sA2[i * 8] = z;
  }
  const int bx = tid >> 4, dx = tid & 15;   // x loader mapping: one value/thread
  {
    float xv = x[(b0 + bx) * (T_SEQ * DIN) + 0 * DIN + dx];
    __bf16 xh, xl; split_bf16(xv, xh, xl);
    sAX[(0 * 64 + (dx >> 3) * 16 + bx) * 8 + (dx & 7)]       = xh;
    sAX[(0 * 64 + (2 + (dx >> 3)) * 16 + bx) * 8 + (dx & 7)] = xl;
    sAX[(1 * 64 + (dx >> 3) * 16 + bx) * 8 + (dx & 7)]       = xl;
    sAX[(1 * 64 + (2 + (dx >> 3)) * 16 + bx) * 8 + (dx & 7)] = xh;
  }
  __syncthreads();

  float c1s[4] = {0.f, 0.f, 0.f, 0.f};  // cell state L1: (unit = w*16+col, batches q*4+r)
  float c2s[4] = {0.f, 0.f, 0.f, 0.f};  // cell state L2 (waves 0,1)
  const int uu = w * 16 + col;

  for (int t = 0; t < T_SEQ; ++t) {
    // ======== Phase A: layer-1 gates (all 4 waves) ========
    bf16x8 a1[4], ax0, ax1;
#pragma unroll
    for (int kb = 0; kb < 4; ++kb) a1[kb] = *(const bf16x8*)&sA1[(kb * 64 + lane) * 8];
    ax0 = *(const bf16x8*)&sAX[(0 * 64 + lane) * 8];
    ax1 = *(const bf16x8*)&sAX[(1 * 64 + lane) * 8];

    float xpre = 0.f;
    if (t + 1 < T_SEQ) xpre = x[(b0 + bx) * (T_SEQ * DIN) + (t + 1) * DIN + dx];

    f32x4 c[4];
#pragma unroll
    for (int g = 0; g < 4; ++g) { c[g][0] = b1v[g]; c[g][1] = b1v[g]; c[g][2] = b1v[g]; c[g][3] = b1v[g]; }
#pragma unroll
    for (int g = 0; g < 4; ++g) {
      c[g] = MFMA(ax0, bih[g], c[g]);            // xh*Wh + xl*Wl
      c[g] = MFMA(ax1, bih[g], c[g]);            // xl*Wh + xh*Wl
#pragma unroll
      for (int kb = 0; kb < 4; ++kb) {
        c[g] = MFMA(a1[kb],     bhh[g][kb], c[g]);   // diagonal terms
        c[g] = MFMA(a1[kb ^ 2], bhh[g][kb], c[g]);   // cross terms (hi<->lo)
      }
    }
    // activations + L1 state update (lane: unit uu, batches q*4+r)
    __bf16 hhi[4], hlo[4];
#pragma unroll
    for (int r = 0; r < 4; ++r) {
      const float iv = fsig(c[0][r]);
      const float fv = fsig(c[1][r]);
      const float gv = ftanhf(c[2][r]);
      const float ov = fsig(c[3][r]);
      const float cc = fmaf(fv, c1s[r], iv * gv);
      c1s[r] = cc;
      split_bf16(ov * ftanhf(cc), hhi[r], hlo[r]);
    }
    __syncthreads();   // B0: all reads of sA1/sAX done

    { // write h1(t) into A-frag order
      const int kbh = uu >> 5;
      const int lnb = ((uu & 31) >> 3) * 16;
      const int jj  = uu & 7;
#pragma unroll
      for (int r = 0; r < 4; ++r) {
        const int m = q * 4 + r;
        sA1[((kbh * 64) + lnb + m) * 8 + jj]       = hhi[r];
        sA1[(((2 + kbh) * 64) + lnb + m) * 8 + jj] = hlo[r];
      }
    }
    if (t + 1 < T_SEQ) { // stage x(t+1)
      __bf16 xh, xl; split_bf16(xpre, xh, xl);
      sAX[(0 * 64 + (dx >> 3) * 16 + bx) * 8 + (dx & 7)]       = xh;
      sAX[(0 * 64 + (2 + (dx >> 3)) * 16 + bx) * 8 + (dx & 7)] = xl;
      sAX[(1 * 64 + (dx >> 3) * 16 + bx) * 8 + (dx & 7)]       = xl;
      sAX[(1 * 64 + (2 + (dx >> 3)) * 16 + bx) * 8 + (dx & 7)] = xh;
    }
    __syncthreads();   // B1: sA1 now holds h1(t)

    // ======== Phase B: layer-2 gates (waves 0,1) ========
    __bf16 h2hi[4], h2lo[4];
    float  h2f[4];
    if (w < 2) {
      bf16x8 a2[4], ah0, ah1;
#pragma unroll
      for (int kb = 0; kb < 4; ++kb) a2[kb] = *(const bf16x8*)&sA1[(kb * 64 + lane) * 8];
      ah0 = *(const bf16x8*)&sA2[(0 * 64 + lane) * 8];
      ah1 = *(const bf16x8*)&sA2[(1 * 64 + lane) * 8];

      f32x4 c2[4];
#pragma unroll
      for (int g = 0; g < 4; ++g) { c2[g][0] = b2v[g]; c2[g][1] = b2v[g]; c2[g][2] = b2v[g]; c2[g][3] = b2v[g]; }
#pragma unroll
      for (int g = 0; g < 4; ++g) {
        const int nt = g * 2 + w;
#pragma unroll
        for (int kb = 0; kb < 4; ++kb) {
          const bf16x8 bb = *(const bf16x8*)&sB2[((nt * 4 + kb) * 64 + lane) * 8];
          c2[g] = MFMA(a2[kb],     bb, c2[g]);
          c2[g] = MFMA(a2[kb ^ 2], bb, c2[g]);
        }
        c2[g] = MFMA(ah0, bh2[g][0], c2[g]);
        c2[g] = MFMA(ah1, bh2[g][1], c2[g]);
        c2[g] = MFMA(ah1, bh2[g][0], c2[g]);
        c2[g] = MFMA(ah0, bh2[g][1], c2[g]);
      }
#pragma unroll
      for (int r = 0; r < 4; ++r) {
        const float iv = fsig(c2[0][r]);
        const float fv = fsig(c2[1][r]);
        const float gv = ftanhf(c2[2][r]);
        const float ov = fsig(c2[3][r]);
        const float cc = fmaf(fv, c2s[r], iv * gv);
        c2s[r] = cc;
        h2f[r] = ov * ftanhf(cc);
        split_bf16(h2f[r], h2hi[r], h2lo[r]);
      }
    }
    __syncthreads();   // B2a: all reads of sA2 (and sA1 in phase B) done

    if (w < 2) {
      const int lnb = ((uu & 31) >> 3) * 16;  // uu in [0,32) for waves 0,1
      const int jj  = uu & 7;
#pragma unroll
      for (int r = 0; r < 4; ++r) {
        const int m = q * 4 + r;
        sA2[((0 * 64) + lnb + m) * 8 + jj] = h2hi[r];
        sA2[((1 * 64) + lnb + m) * 8 + jj] = h2lo[r];
        if (t == T_SEQ - 1) sH2f[m * 32 + uu] = h2f[r];
      }
    }
    __syncthreads();   // B2
  }

  // ======== FC epilogue ========
  if (tid < NB) {
    float s = bfc[0];
#pragma unroll
    for (int j = 0; j < 32; ++j) s = fmaf(Wfc[j], sH2f[tid * 32 + j], s);
    out[b0 + tid] = s;
  }
}

extern "C" void kernel_launch(void* const* d_in, const int* in_sizes, int n_in,
                              void* d_out, int out_size, void* d_ws, size_t ws_size,
                              hipStream_t stream) {
  (void)in_sizes; (void)n_in; (void)out_size; (void)d_ws; (void)ws_size;
  const float* x    = (const float*)d_in[0];
  const float* Wih1 = (const float*)d_in[1];
  const float* Whh1 = (const float*)d_in[2];
  const float* bih1 = (const float*)d_in[3];
  const float* bhh1 = (const float*)d_in[4];
  const float* Wih2 = (const float*)d_in[5];
  const float* Whh2 = (const float*)d_in[6];
  const float* bih2 = (const float*)d_in[7];
  const float* bhh2 = (const float*)d_in[8];
  const float* Wfc  = (const float*)d_in[9];
  const float* bfc  = (const float*)d_in[10];
  float* out = (float*)d_out;

  hipLaunchKernelGGL(lstm_mfma_kernel, dim3(4096 / NB), dim3(256), 0, stream,
                     x, Wih1, Whh1, bih1, bhh1, Wih2, Whh2, bih2, bhh2, Wfc, bfc, out);
}